// Round 6
// baseline (250.066 us; speedup 1.0000x reference)
//
#include <hip/hip_runtime.h>
#include <hip/hip_bf16.h>
#include <stdint.h>

// Problem: B=4096, I=H=1024. pre_ih = x@w_ih^T, pre_hh = h@w_hh^T (each 4096x4096,
// K=1024), per-gate LN over H, gate math, c_new LN, outputs h_new||c_new (fp32).

#define HDIM 1024
#define BATCH 4096
#define NGATE 4096   /* 4*H */
#define KDIM 1024

typedef __bf16 bf16x8 __attribute__((ext_vector_type(8)));
typedef float f32x4 __attribute__((ext_vector_type(4)));
typedef unsigned short ushort8_t __attribute__((ext_vector_type(8)));

__device__ __forceinline__ unsigned short f2bf(float f) {
  unsigned int u = __builtin_bit_cast(unsigned int, f);
  unsigned int r = (u + 0x7fffu + ((u >> 16) & 1u)) >> 16;
  return (unsigned short)r;
}

__device__ __forceinline__ float bf2f(unsigned short s) {
  unsigned int u = ((unsigned int)s) << 16;
  return __builtin_bit_cast(float, u);
}

__device__ __forceinline__ void gl_lds16(const void* g, void* l) {
  // async global->LDS, 16B per lane; LDS dest = wave-uniform base + lane*16
  __builtin_amdgcn_global_load_lds(
      (__attribute__((address_space(1))) unsigned int*)g,
      (__attribute__((address_space(3))) unsigned int*)l,
      16, 0, 0);
}

// ---------------- cast fp32 -> bf16 (x, h, w_ih, w_hh) ----------------
__global__ __launch_bounds__(256) void cast_bf16_kernel(
    const float* __restrict__ x, const float* __restrict__ h,
    const float* __restrict__ wi, const float* __restrict__ wh,
    unsigned short* __restrict__ xb, unsigned short* __restrict__ hb,
    unsigned short* __restrict__ wib, unsigned short* __restrict__ whb) {
  const float* src;
  unsigned short* dst;
  switch (blockIdx.y) {
    case 0: src = x;  dst = xb;  break;
    case 1: src = h;  dst = hb;  break;
    case 2: src = wi; dst = wib; break;
    default: src = wh; dst = whb; break;
  }
  size_t i = ((size_t)blockIdx.x * 256 + threadIdx.x) * 4;
  float4 v = *(const float4*)(src + i);
  ushort4 o;
  o.x = f2bf(v.x); o.y = f2bf(v.y); o.z = f2bf(v.z); o.w = f2bf(v.w);
  *(ushort4*)(dst + i) = o;
}

// ---------------- bf16 MFMA GEMM: C[m][n] = sum_k A[m][k]*B[n][k] ----------------
// R4 structure (72 us / 954 TF): BM=BN=128, BK=64, 4 waves 2x2, wave tile 64x64
// (4x4 MFMA 16x16x32), 32 KB LDS. Two 16-MFMA k-steps per barrier-pair.
// LDS rows 64 elems (8 granules of 16B), XOR-swizzle granule c of row r stored
// at c ^ (r&7) (fetch-side, since global_load_lds pins LDS dest to lane*16;
// inverted at ds_read) -> all read phases 2 lanes/bank-group = conflict-free.
// Epilogue additionally emits per-row partial LN stats (sum, sumsq over this
// wave's 64 n-cols): stats[m*64 + blockIdx.y*2 + (wave&1)], each slot written
// exactly once (race-free, no atomics).
__global__ __launch_bounds__(256, 4) void gemm_bt_kernel(
    const unsigned short* __restrict__ A0, const unsigned short* __restrict__ B0,
    unsigned short* __restrict__ C0, float2* __restrict__ S0,
    const unsigned short* __restrict__ A1, const unsigned short* __restrict__ B1,
    unsigned short* __restrict__ C1, float2* __restrict__ S1) {
  const unsigned short* A = blockIdx.z ? A1 : A0;
  const unsigned short* B = blockIdx.z ? B1 : B0;
  unsigned short* C = blockIdx.z ? C1 : C0;
  float2* SB = blockIdx.z ? S1 : S0;

  __shared__ alignas(16) unsigned short As[128 * 64];  // 16 KB
  __shared__ alignas(16) unsigned short Bs[128 * 64];  // 16 KB

  const int tid = threadIdx.x;
  const int wave = tid >> 6;
  const int lane = tid & 63;
  const int bm = blockIdx.x * 128;
  const int bn = blockIdx.y * 128;
  const int wm = (wave >> 1) * 64;
  const int wn = (wave & 1) * 64;

  // staging: each inst covers 8 rows x 128B; lane -> row lane>>3,
  // fetch-side swizzled granule (lane&7)^(lane>>3)
  const int srow = lane >> 3;
  const int scol = (((lane & 7) ^ (lane >> 3)) * 8);

  f32x4 acc[4][4];
#pragma unroll
  for (int i = 0; i < 4; ++i)
#pragma unroll
    for (int j = 0; j < 4; ++j)
#pragma unroll
      for (int r = 0; r < 4; ++r) acc[i][j][r] = 0.0f;

  const int m15 = lane & 15;
  const int quad = lane >> 4;

  for (int k0 = 0; k0 < KDIM; k0 += 64) {
#pragma unroll
    for (int t = 0; t < 4; ++t) {
      int R = wave * 32 + t * 8;  // wave-uniform row base
      gl_lds16(A + (size_t)(bm + R + srow) * KDIM + k0 + scol, &As[R * 64]);
      gl_lds16(B + (size_t)(bn + R + srow) * KDIM + k0 + scol, &Bs[R * 64]);
    }
    __syncthreads();

#pragma unroll
    for (int s = 0; s < 2; ++s) {
      const int gran = (((4 * s + quad) ^ (m15 & 7)) * 8);
      bf16x8 af[4], bfr[4];
#pragma unroll
      for (int i = 0; i < 4; ++i)
        af[i] = *(const bf16x8*)&As[(wm + i * 16 + m15) * 64 + gran];
#pragma unroll
      for (int j = 0; j < 4; ++j)
        bfr[j] = *(const bf16x8*)&Bs[(wn + j * 16 + m15) * 64 + gran];

#pragma unroll
      for (int i = 0; i < 4; ++i)
#pragma unroll
        for (int j = 0; j < 4; ++j)
          acc[i][j] = __builtin_amdgcn_mfma_f32_16x16x32_bf16(af[i], bfr[j], acc[i][j], 0, 0, 0);
    }

    __syncthreads();
  }

  // D layout: row m = (lane>>4)*4 + r, col n = lane&15  [m89/m91 verified]
#pragma unroll
  for (int i = 0; i < 4; ++i)
#pragma unroll
    for (int j = 0; j < 4; ++j)
#pragma unroll
      for (int r = 0; r < 4; ++r) {
        int m = bm + wm + i * 16 + quad * 4 + r;
        int n = bn + wn + j * 16 + m15;
        C[(size_t)m * NGATE + n] = f2bf(acc[i][j][r]);
      }

  // per-row partial LN stats over this wave's 64 cols (16 rows per lane-quad)
#pragma unroll
  for (int i = 0; i < 4; ++i)
#pragma unroll
    for (int r = 0; r < 4; ++r) {
      float s = 0.f, q = 0.f;
#pragma unroll
      for (int j = 0; j < 4; ++j) {
        float v = acc[i][j][r];
        s += v; q += v * v;
      }
#pragma unroll
      for (int o = 1; o < 16; o <<= 1) {  // reduce across the 16 n-lanes
        s += __shfl_xor(s, o, 64);
        q += __shfl_xor(q, o, 64);
      }
      if (m15 == 0) {
        int m = bm + wm + i * 16 + quad * 4 + r;
        SB[(size_t)m * 64 + blockIdx.y * 2 + (wave & 1)] = make_float2(s, q);
      }
    }
}

// ---------------- LN + gates + cell update ----------------
// Stats come precomputed from the GEMM epilogue: 64 float2 partials per
// (row, mat), 16 per gate. Waves 0/1 reduce them (no global re-read of pre);
// then one pass: normalize, gate math, block reduction for c_new LN.
__device__ __forceinline__ float fast_sigmoid(float x) {
  return __builtin_amdgcn_rcpf(1.0f + __expf(-x));
}
__device__ __forceinline__ float fast_tanh(float x) {
  // 1 - 2/(exp(2x)+1); saturates correctly at +-1
  return 1.0f - 2.0f * __builtin_amdgcn_rcpf(__expf(2.0f * x) + 1.0f);
}

__global__ __launch_bounds__(256) void ln_gate_kernel(
    const unsigned short* __restrict__ pih, const unsigned short* __restrict__ phh,
    const float2* __restrict__ S0, const float2* __restrict__ S1,
    const float* __restrict__ c, const float* __restrict__ b_ih,
    const float* __restrict__ gamma, const float* __restrict__ beta,
    float* __restrict__ h_out, float* __restrict__ c_out) {
  __shared__ float lds[32];  // [g*4 + mat*2 + {mu,rs}]; [16..31]: scratch
  const int b = blockIdx.x;
  const int t = threadIdx.x;
  const int wave = t >> 6;
  const int lane = t & 63;
  const float inv_h = 1.0f / 1024.0f;
  const float eps = 1e-5f;

  // ---- Phase A: combine 16 partials per (gate, mat) ----
  if (t < 128) {
    const float2* S = wave ? S1 : S0;
    float2 p = S[(size_t)b * 64 + lane];  // lane = g*16 + part
    float s = p.x, q = p.y;
#pragma unroll
    for (int o = 1; o < 16; o <<= 1) {
      s += __shfl_xor(s, o, 64);
      q += __shfl_xor(q, o, 64);
    }
    if ((lane & 15) == 0) {
      int g = lane >> 4;
      float mu = s * inv_h;
      lds[g * 4 + wave * 2 + 0] = mu;
      lds[g * 4 + wave * 2 + 1] = rsqrtf(q * inv_h - mu * mu + eps);
    }
  }
  __syncthreads();

  // ---- Phase B: normalize + gate math + c_new LN ----
  const int j = t * 4;
  float gate[4][4];
#pragma unroll
  for (int g = 0; g < 4; ++g) {
    float mu0 = lds[g * 4 + 0], rs0 = lds[g * 4 + 1];
    float mu1 = lds[g * 4 + 2], rs1 = lds[g * 4 + 3];
    ushort4 a4 = *(const ushort4*)&pih[(size_t)b * NGATE + g * HDIM + j];
    ushort4 e4 = *(const ushort4*)&phh[(size_t)b * NGATE + g * HDIM + j];
    float vih[4] = {bf2f(a4.x), bf2f(a4.y), bf2f(a4.z), bf2f(a4.w)};
    float vhh[4] = {bf2f(e4.x), bf2f(e4.y), bf2f(e4.z), bf2f(e4.w)};
    float4 g0 = *(const float4*)&gamma[(2 * g) * HDIM + j];
    float4 b0 = *(const float4*)&beta[(2 * g) * HDIM + j];
    float4 g1 = *(const float4*)&gamma[(2 * g + 1) * HDIM + j];
    float4 b1 = *(const float4*)&beta[(2 * g + 1) * HDIM + j];
    float4 bb = *(const float4*)&b_ih[g * HDIM + j];
    const float* g0p = &g0.x; const float* b0p = &b0.x;
    const float* g1p = &g1.x; const float* b1p = &b1.x;
    const float* bbp = &bb.x;
#pragma unroll
    for (int r = 0; r < 4; ++r) {
      float gih = g0p[r] * ((vih[r] - mu0) * rs0) + b0p[r];
      float ghh = g1p[r] * ((vhh[r] - mu1) * rs1) + b1p[r];
      gate[g][r] = gih + ghh + bbp[r];
    }
  }

  float4 cv4 = *(const float4*)&c[(size_t)b * HDIM + j];
  const float* cvp = &cv4.x;
  float cn[4], ov[4];
  float s2 = 0.f, q2 = 0.f;
#pragma unroll
  for (int r = 0; r < 4; ++r) {
    float iv = fast_sigmoid(gate[0][r]);
    float fv = fast_sigmoid(gate[1][r]);
    float av = fast_tanh(gate[2][r]);
    ov[r] = fast_sigmoid(gate[3][r]);
    float cvn = fv * cvp[r] + iv * av;
    cn[r] = cvn;
    s2 += cvn; q2 += cvn * cvn;
  }
#pragma unroll
  for (int o = 1; o < 64; o <<= 1) {
    s2 += __shfl_xor(s2, o, 64);
    q2 += __shfl_xor(q2, o, 64);
  }
  __syncthreads();  // stats already consumed into registers
  if (lane == 0) { lds[16 + wave * 2] = s2; lds[16 + wave * 2 + 1] = q2; }
  __syncthreads();
  s2 = lds[16] + lds[18] + lds[20] + lds[22];
  q2 = lds[17] + lds[19] + lds[21] + lds[23];
  float mu = s2 * inv_h;
  float rs = rsqrtf(q2 * inv_h - mu * mu + eps);

  float4 g8 = *(const float4*)&gamma[8 * HDIM + j];
  float4 b8 = *(const float4*)&beta[8 * HDIM + j];
  const float* g8p = &g8.x; const float* b8p = &b8.x;
  float4 ho, co;
  float* hop = &ho.x; float* cop = &co.x;
#pragma unroll
  for (int r = 0; r < 4; ++r) {
    float ln = g8p[r] * ((cn[r] - mu) * rs) + b8p[r];
    hop[r] = ov[r] * fast_tanh(ln);
    cop[r] = cn[r];
  }
  *(float4*)&h_out[(size_t)b * HDIM + j] = ho;
  *(float4*)&c_out[(size_t)b * HDIM + j] = co;
}

extern "C" void kernel_launch(void* const* d_in, const int* in_sizes, int n_in,
                              void* d_out, int out_size, void* d_ws, size_t ws_size,
                              hipStream_t stream) {
  const float* x     = (const float*)d_in[0];
  const float* h     = (const float*)d_in[1];
  const float* c     = (const float*)d_in[2];
  const float* w_ih  = (const float*)d_in[3];
  const float* w_hh  = (const float*)d_in[4];
  const float* b_ih  = (const float*)d_in[5];
  const float* gamma = (const float*)d_in[6];
  const float* beta  = (const float*)d_in[7];
  // d_in[8] = time (unused)

  // workspace layout (bytes):
  //   0    xb  bf16 4096x1024 (8MB) | 8M hb | 16M wib | 24M whb
  //   32M  pih bf16 4096x4096 (32MB) | 64M phh (32MB)
  //   96M  stat0 float2 4096x64 (2MB) | 98M stat1 (2MB)   total 100 MB
  char* ws = (char*)d_ws;
  unsigned short* xb  = (unsigned short*)(ws);
  unsigned short* hb  = (unsigned short*)(ws + (size_t)8 * 1024 * 1024);
  unsigned short* wib = (unsigned short*)(ws + (size_t)16 * 1024 * 1024);
  unsigned short* whb = (unsigned short*)(ws + (size_t)24 * 1024 * 1024);
  unsigned short* pih = (unsigned short*)(ws + (size_t)32 * 1024 * 1024);
  unsigned short* phh = (unsigned short*)(ws + (size_t)64 * 1024 * 1024);
  float2* stat0 = (float2*)(ws + (size_t)96 * 1024 * 1024);
  float2* stat1 = (float2*)(ws + (size_t)98 * 1024 * 1024);

  dim3 cgrid(4096, 4, 1);  // 4 arrays x 4M elems, 4 elems/thread
  cast_bf16_kernel<<<cgrid, 256, 0, stream>>>(x, h, w_ih, w_hh, xb, hb, wib, whb);

  dim3 ggrid(32, 32, 2);   // 128x128 tiles over 4096x4096; z: 0=ih, 1=hh
  gemm_bt_kernel<<<ggrid, 256, 0, stream>>>(xb, wib, pih, stat0, hb, whb, phh, stat1);

  float* h_out = (float*)d_out;
  float* c_out = h_out + (size_t)BATCH * HDIM;
  ln_gate_kernel<<<4096, 256, 0, stream>>>(pih, phh, stat0, stat1, c, b_ih, gamma, beta, h_out, c_out);
}

// Round 7
// 243.593 us; speedup vs baseline: 1.0266x; 1.0266x over previous
//
#include <hip/hip_runtime.h>
#include <hip/hip_bf16.h>
#include <stdint.h>

// Problem: B=4096, I=H=1024. pre_ih = x@w_ih^T, pre_hh = h@w_hh^T (each 4096x4096,
// K=1024), per-gate LN over H, gate math, c_new LN, outputs h_new||c_new (fp32).

#define HDIM 1024
#define BATCH 4096
#define NGATE 4096   /* 4*H */
#define KDIM 1024

typedef __bf16 bf16x8 __attribute__((ext_vector_type(8)));
typedef float f32x4 __attribute__((ext_vector_type(4)));
typedef unsigned short ushort8_t __attribute__((ext_vector_type(8)));

__device__ __forceinline__ unsigned short f2bf(float f) {
  unsigned int u = __builtin_bit_cast(unsigned int, f);
  unsigned int r = (u + 0x7fffu + ((u >> 16) & 1u)) >> 16;
  return (unsigned short)r;
}

__device__ __forceinline__ float bf2f(unsigned short s) {
  unsigned int u = ((unsigned int)s) << 16;
  return __builtin_bit_cast(float, u);
}

__device__ __forceinline__ void gl_lds16(const void* g, void* l) {
  // async global->LDS, 16B per lane; LDS dest = wave-uniform base + lane*16
  __builtin_amdgcn_global_load_lds(
      (__attribute__((address_space(1))) unsigned int*)g,
      (__attribute__((address_space(3))) unsigned int*)l,
      16, 0, 0);
}

// ---------------- cast fp32 -> bf16 (x, h, w_ih, w_hh) ----------------
__global__ __launch_bounds__(256) void cast_bf16_kernel(
    const float* __restrict__ x, const float* __restrict__ h,
    const float* __restrict__ wi, const float* __restrict__ wh,
    unsigned short* __restrict__ xb, unsigned short* __restrict__ hb,
    unsigned short* __restrict__ wib, unsigned short* __restrict__ whb) {
  const float* src;
  unsigned short* dst;
  switch (blockIdx.y) {
    case 0: src = x;  dst = xb;  break;
    case 1: src = h;  dst = hb;  break;
    case 2: src = wi; dst = wib; break;
    default: src = wh; dst = whb; break;
  }
  size_t i = ((size_t)blockIdx.x * 256 + threadIdx.x) * 4;
  float4 v = *(const float4*)(src + i);
  ushort4 o;
  o.x = f2bf(v.x); o.y = f2bf(v.y); o.z = f2bf(v.z); o.w = f2bf(v.w);
  *(ushort4*)(dst + i) = o;
}

// ---------------- bf16 MFMA GEMM: C[m][n] = sum_k A[m][k]*B[n][k] ----------------
// R4 K-loop (72us/954TF): BM=BN=128, BK=64, 4 waves 2x2, wave tile 64x64,
// 32 KB LDS, XOR-swizzled (fetch-side, inverted at ds_read) -> 0 conflicts.
// OPERAND-SWAPPED MFMA: mfma(b_frag, a_frag, acc) gives D[row=n][col=m], i.e.
// reg dimension = 4 consecutive n at fixed m=lane&15. Epilogue packs each
// acc[i][j] into ONE 8-byte ushort4 store (16 stores vs 64 scalar shorts),
// and per-row(m) LN stats reduce across quads only: 2 shfl levels x 4 i-tiles
// = 16 shuffles (R6's per-row-over-16-lane scheme needed 128 -> +13us).
// stats slot: SB[m*64 + blockIdx.y*2 + (wave&1)], written exactly once.
__global__ __launch_bounds__(256, 4) void gemm_bt_kernel(
    const unsigned short* __restrict__ A0, const unsigned short* __restrict__ B0,
    unsigned short* __restrict__ C0, float2* __restrict__ S0,
    const unsigned short* __restrict__ A1, const unsigned short* __restrict__ B1,
    unsigned short* __restrict__ C1, float2* __restrict__ S1) {
  const unsigned short* A = blockIdx.z ? A1 : A0;
  const unsigned short* B = blockIdx.z ? B1 : B0;
  unsigned short* C = blockIdx.z ? C1 : C0;
  float2* SB = blockIdx.z ? S1 : S0;

  __shared__ alignas(16) unsigned short As[128 * 64];  // 16 KB
  __shared__ alignas(16) unsigned short Bs[128 * 64];  // 16 KB

  const int tid = threadIdx.x;
  const int wave = tid >> 6;
  const int lane = tid & 63;
  const int bm = blockIdx.x * 128;
  const int bn = blockIdx.y * 128;
  const int wm = (wave >> 1) * 64;
  const int wn = (wave & 1) * 64;

  // staging: each inst covers 8 rows x 128B; lane -> row lane>>3,
  // fetch-side swizzled granule (lane&7)^(lane>>3)
  const int srow = lane >> 3;
  const int scol = (((lane & 7) ^ (lane >> 3)) * 8);

  f32x4 acc[4][4];
#pragma unroll
  for (int i = 0; i < 4; ++i)
#pragma unroll
    for (int j = 0; j < 4; ++j)
#pragma unroll
      for (int r = 0; r < 4; ++r) acc[i][j][r] = 0.0f;

  const int m15 = lane & 15;
  const int quad = lane >> 4;

  for (int k0 = 0; k0 < KDIM; k0 += 64) {
#pragma unroll
    for (int t = 0; t < 4; ++t) {
      int R = wave * 32 + t * 8;  // wave-uniform row base
      gl_lds16(A + (size_t)(bm + R + srow) * KDIM + k0 + scol, &As[R * 64]);
      gl_lds16(B + (size_t)(bn + R + srow) * KDIM + k0 + scol, &Bs[R * 64]);
    }
    __syncthreads();

#pragma unroll
    for (int s = 0; s < 2; ++s) {
      const int gran = (((4 * s + quad) ^ (m15 & 7)) * 8);
      bf16x8 af[4], bfr[4];
#pragma unroll
      for (int i = 0; i < 4; ++i)
        af[i] = *(const bf16x8*)&As[(wm + i * 16 + m15) * 64 + gran];
#pragma unroll
      for (int j = 0; j < 4; ++j)
        bfr[j] = *(const bf16x8*)&Bs[(wn + j * 16 + m15) * 64 + gran];

      // operand-swapped: D[row=n][col=m]
#pragma unroll
      for (int i = 0; i < 4; ++i)
#pragma unroll
        for (int j = 0; j < 4; ++j)
          acc[i][j] = __builtin_amdgcn_mfma_f32_16x16x32_bf16(bfr[j], af[i], acc[i][j], 0, 0, 0);
    }

    __syncthreads();
  }

  // Swapped D layout: n = j*16 + quad*4 + r (reg dim), m = i*16 + m15.
  // Each acc[i][j] = 4 consecutive n at fixed m -> one 8B ushort4 store.
#pragma unroll
  for (int i = 0; i < 4; ++i) {
    unsigned short* Crow = C + (size_t)(bm + wm + i * 16 + m15) * NGATE + bn + wn + quad * 4;
#pragma unroll
    for (int j = 0; j < 4; ++j) {
      ushort4 pk;
      pk.x = f2bf(acc[i][j][0]);
      pk.y = f2bf(acc[i][j][1]);
      pk.z = f2bf(acc[i][j][2]);
      pk.w = f2bf(acc[i][j][3]);
      *(ushort4*)(Crow + j * 16) = pk;
    }
  }

  // per-row(m) partial LN stats over this wave's 64 n-cols: in-lane sum over
  // j,r (16 vals), then reduce over the 4 quads (2 shfl levels).
#pragma unroll
  for (int i = 0; i < 4; ++i) {
    float s = 0.f, q = 0.f;
#pragma unroll
    for (int j = 0; j < 4; ++j)
#pragma unroll
      for (int r = 0; r < 4; ++r) {
        float v = acc[i][j][r];
        s += v; q += v * v;
      }
    s += __shfl_xor(s, 16, 64); q += __shfl_xor(q, 16, 64);
    s += __shfl_xor(s, 32, 64); q += __shfl_xor(q, 32, 64);
    if (quad == 0) {
      int m = bm + wm + i * 16 + m15;
      SB[(size_t)m * 64 + blockIdx.y * 2 + (wave & 1)] = make_float2(s, q);
    }
  }
}

// ---------------- LN + gates + cell update ----------------
// Stats come precomputed from the GEMM epilogue: 64 float2 partials per
// (row, mat), 16 per gate. Waves 0/1 reduce them (no global re-read of pre);
// then one pass: normalize, gate math, block reduction for c_new LN.
__device__ __forceinline__ float fast_sigmoid(float x) {
  return __builtin_amdgcn_rcpf(1.0f + __expf(-x));
}
__device__ __forceinline__ float fast_tanh(float x) {
  // 1 - 2/(exp(2x)+1); saturates correctly at +-1
  return 1.0f - 2.0f * __builtin_amdgcn_rcpf(__expf(2.0f * x) + 1.0f);
}

__global__ __launch_bounds__(256) void ln_gate_kernel(
    const unsigned short* __restrict__ pih, const unsigned short* __restrict__ phh,
    const float2* __restrict__ S0, const float2* __restrict__ S1,
    const float* __restrict__ c, const float* __restrict__ b_ih,
    const float* __restrict__ gamma, const float* __restrict__ beta,
    float* __restrict__ h_out, float* __restrict__ c_out) {
  __shared__ float lds[32];  // [g*4 + mat*2 + {mu,rs}]; [16..31]: scratch
  const int b = blockIdx.x;
  const int t = threadIdx.x;
  const int wave = t >> 6;
  const int lane = t & 63;
  const float inv_h = 1.0f / 1024.0f;
  const float eps = 1e-5f;

  // ---- Phase A: combine 16 partials per (gate, mat) ----
  if (t < 128) {
    const float2* S = wave ? S1 : S0;
    float2 p = S[(size_t)b * 64 + lane];  // lane = g*16 + part
    float s = p.x, q = p.y;
#pragma unroll
    for (int o = 1; o < 16; o <<= 1) {
      s += __shfl_xor(s, o, 64);
      q += __shfl_xor(q, o, 64);
    }
    if ((lane & 15) == 0) {
      int g = lane >> 4;
      float mu = s * inv_h;
      lds[g * 4 + wave * 2 + 0] = mu;
      lds[g * 4 + wave * 2 + 1] = rsqrtf(q * inv_h - mu * mu + eps);
    }
  }
  __syncthreads();

  // ---- Phase B: normalize + gate math + c_new LN ----
  const int j = t * 4;
  float gate[4][4];
#pragma unroll
  for (int g = 0; g < 4; ++g) {
    float mu0 = lds[g * 4 + 0], rs0 = lds[g * 4 + 1];
    float mu1 = lds[g * 4 + 2], rs1 = lds[g * 4 + 3];
    ushort4 a4 = *(const ushort4*)&pih[(size_t)b * NGATE + g * HDIM + j];
    ushort4 e4 = *(const ushort4*)&phh[(size_t)b * NGATE + g * HDIM + j];
    float vih[4] = {bf2f(a4.x), bf2f(a4.y), bf2f(a4.z), bf2f(a4.w)};
    float vhh[4] = {bf2f(e4.x), bf2f(e4.y), bf2f(e4.z), bf2f(e4.w)};
    float4 g0 = *(const float4*)&gamma[(2 * g) * HDIM + j];
    float4 b0 = *(const float4*)&beta[(2 * g) * HDIM + j];
    float4 g1 = *(const float4*)&gamma[(2 * g + 1) * HDIM + j];
    float4 b1 = *(const float4*)&beta[(2 * g + 1) * HDIM + j];
    float4 bb = *(const float4*)&b_ih[g * HDIM + j];
    const float* g0p = &g0.x; const float* b0p = &b0.x;
    const float* g1p = &g1.x; const float* b1p = &b1.x;
    const float* bbp = &bb.x;
#pragma unroll
    for (int r = 0; r < 4; ++r) {
      float gih = g0p[r] * ((vih[r] - mu0) * rs0) + b0p[r];
      float ghh = g1p[r] * ((vhh[r] - mu1) * rs1) + b1p[r];
      gate[g][r] = gih + ghh + bbp[r];
    }
  }

  float4 cv4 = *(const float4*)&c[(size_t)b * HDIM + j];
  const float* cvp = &cv4.x;
  float cn[4], ov[4];
  float s2 = 0.f, q2 = 0.f;
#pragma unroll
  for (int r = 0; r < 4; ++r) {
    float iv = fast_sigmoid(gate[0][r]);
    float fv = fast_sigmoid(gate[1][r]);
    float av = fast_tanh(gate[2][r]);
    ov[r] = fast_sigmoid(gate[3][r]);
    float cvn = fv * cvp[r] + iv * av;
    cn[r] = cvn;
    s2 += cvn; q2 += cvn * cvn;
  }
#pragma unroll
  for (int o = 1; o < 64; o <<= 1) {
    s2 += __shfl_xor(s2, o, 64);
    q2 += __shfl_xor(q2, o, 64);
  }
  __syncthreads();  // stats already consumed into registers
  if (lane == 0) { lds[16 + wave * 2] = s2; lds[16 + wave * 2 + 1] = q2; }
  __syncthreads();
  s2 = lds[16] + lds[18] + lds[20] + lds[22];
  q2 = lds[17] + lds[19] + lds[21] + lds[23];
  float mu = s2 * inv_h;
  float rs = rsqrtf(q2 * inv_h - mu * mu + eps);

  float4 g8 = *(const float4*)&gamma[8 * HDIM + j];
  float4 b8 = *(const float4*)&beta[8 * HDIM + j];
  const float* g8p = &g8.x; const float* b8p = &b8.x;
  float4 ho, co;
  float* hop = &ho.x; float* cop = &co.x;
#pragma unroll
  for (int r = 0; r < 4; ++r) {
    float ln = g8p[r] * ((cn[r] - mu) * rs) + b8p[r];
    hop[r] = ov[r] * fast_tanh(ln);
    cop[r] = cn[r];
  }
  *(float4*)&h_out[(size_t)b * HDIM + j] = ho;
  *(float4*)&c_out[(size_t)b * HDIM + j] = co;
}

extern "C" void kernel_launch(void* const* d_in, const int* in_sizes, int n_in,
                              void* d_out, int out_size, void* d_ws, size_t ws_size,
                              hipStream_t stream) {
  const float* x     = (const float*)d_in[0];
  const float* h     = (const float*)d_in[1];
  const float* c     = (const float*)d_in[2];
  const float* w_ih  = (const float*)d_in[3];
  const float* w_hh  = (const float*)d_in[4];
  const float* b_ih  = (const float*)d_in[5];
  const float* gamma = (const float*)d_in[6];
  const float* beta  = (const float*)d_in[7];
  // d_in[8] = time (unused)

  // workspace layout (bytes):
  //   0    xb  bf16 4096x1024 (8MB) | 8M hb | 16M wib | 24M whb
  //   32M  pih bf16 4096x4096 (32MB) | 64M phh (32MB)
  //   96M  stat0 float2 4096x64 (2MB) | 98M stat1 (2MB)   total 100 MB
  char* ws = (char*)d_ws;
  unsigned short* xb  = (unsigned short*)(ws);
  unsigned short* hb  = (unsigned short*)(ws + (size_t)8 * 1024 * 1024);
  unsigned short* wib = (unsigned short*)(ws + (size_t)16 * 1024 * 1024);
  unsigned short* whb = (unsigned short*)(ws + (size_t)24 * 1024 * 1024);
  unsigned short* pih = (unsigned short*)(ws + (size_t)32 * 1024 * 1024);
  unsigned short* phh = (unsigned short*)(ws + (size_t)64 * 1024 * 1024);
  float2* stat0 = (float2*)(ws + (size_t)96 * 1024 * 1024);
  float2* stat1 = (float2*)(ws + (size_t)98 * 1024 * 1024);

  dim3 cgrid(4096, 4, 1);  // 4 arrays x 4M elems, 4 elems/thread
  cast_bf16_kernel<<<cgrid, 256, 0, stream>>>(x, h, w_ih, w_hh, xb, hb, wib, whb);

  dim3 ggrid(32, 32, 2);   // 128x128 tiles over 4096x4096; z: 0=ih, 1=hh
  gemm_bt_kernel<<<ggrid, 256, 0, stream>>>(xb, wib, pih, stat0, hb, whb, phh, stat1);

  float* h_out = (float*)d_out;
  float* c_out = h_out + (size_t)BATCH * HDIM;
  ln_gate_kernel<<<4096, 256, 0, stream>>>(pih, phh, stat0, stat1, c, b_ih, gamma, beta, h_out, c_out);
}